// Round 1
// baseline (704.022 us; speedup 1.0000x reference)
//
#include <hip/hip_runtime.h>
#include <cfloat>

// Problem constants
#define B_    256
#define S_    512
#define H_    768
#define LLEFT 256
#define LT    64
#define OUTD  3

// ---------------------------------------------------------------------------
// Kernel 1: per-batch ragged span max-pool + concat [pooled | span_max]
// One block per batch sample, 256 threads.
// ---------------------------------------------------------------------------
__global__ void pool_cat_kernel(const float* __restrict__ SE,        // [B,S,H]
                                const float* __restrict__ pooled,    // [B,H]
                                const int* __restrict__ left_ids,    // [B,LLEFT]
                                const int* __restrict__ t_ids,       // [B,LT]
                                float* __restrict__ cat)             // [B,2H]
{
    const int b = blockIdx.x;
    const int t = threadIdx.x;

    __shared__ int s_cnt[2];
    if (t < 2) s_cnt[t] = 0;
    __syncthreads();

    if (t < LLEFT && left_ids[b * LLEFT + t] != 0) atomicAdd(&s_cnt[0], 1);
    if (t < LT    && t_ids[b * LT + t]       != 0) atomicAdd(&s_cnt[1], 1);
    __syncthreads();

    const int start = s_cnt[0] - 1;   // left_len
    const int len   = s_cnt[1] - 2;   // target_len  (>=1 by construction)

    const float* se_b = SE + ((size_t)b * S_ + start) * H_;
    for (int h = t; h < H_; h += 256) {
        float m = -FLT_MAX;
        const float* p = se_b + h;
        for (int r = 0; r < len; ++r) m = fmaxf(m, p[(size_t)r * H_]);
        cat[(size_t)b * (2 * H_) + h]       = pooled[(size_t)b * H_ + h];
        cat[(size_t)b * (2 * H_) + H_ + h]  = m;
    }
}

// ---------------------------------------------------------------------------
// Tiled fp32 GEMM: C = act(A[MxK] @ W[KxN] + bias[N]), row-major everywhere.
// BM=BN=64, BK=16, 256 threads, 4x4 micro-tile per thread.
// M,N multiples of 64; K multiple of 16 (true for all layers here).
// ---------------------------------------------------------------------------
template <bool TANH>
__global__ __launch_bounds__(256)
void gemm_bias_act(const float* __restrict__ A,
                   const float* __restrict__ W,
                   const float* __restrict__ bias,
                   float* __restrict__ C,
                   int M, int N, int K)
{
    constexpr int BM = 64, BN = 64, BK = 16, TM = 4, TN = 4;
    __shared__ float As[BK][BM + 4];   // +4 pad: store-transpose conflicts -> 2-way (free)
    __shared__ float Bs[BK][BN];

    const int tid  = threadIdx.x;
    const int trow = tid / (BN / TN);  // 0..15
    const int tcol = tid % (BN / TN);  // 0..15
    const int mbase = blockIdx.y * BM;
    const int nbase = blockIdx.x * BN;

    // A-tile load mapping: each thread loads float4 along K
    const int a_m = tid >> 2;          // 0..63
    const int a_k = (tid & 3) * 4;     // 0,4,8,12
    // B-tile load mapping: each thread loads float4 along N
    const int b_k = tid >> 4;          // 0..15
    const int b_n = (tid & 15) * 4;    // 0..60

    float acc[TM][TN] = {};

    for (int k0 = 0; k0 < K; k0 += BK) {
        // stage A (transposed into LDS)
        const float4 a4 = *(const float4*)(A + (size_t)(mbase + a_m) * K + k0 + a_k);
        As[a_k + 0][a_m] = a4.x;
        As[a_k + 1][a_m] = a4.y;
        As[a_k + 2][a_m] = a4.z;
        As[a_k + 3][a_m] = a4.w;
        // stage B
        *(float4*)&Bs[b_k][b_n] = *(const float4*)(W + (size_t)(k0 + b_k) * N + nbase + b_n);
        __syncthreads();

#pragma unroll
        for (int k = 0; k < BK; ++k) {
            const float4 av = *(const float4*)&As[k][trow * TM];
            const float4 bv = *(const float4*)&Bs[k][tcol * TN];
            const float a[TM] = {av.x, av.y, av.z, av.w};
            const float b[TN] = {bv.x, bv.y, bv.z, bv.w};
#pragma unroll
            for (int i = 0; i < TM; ++i)
#pragma unroll
                for (int j = 0; j < TN; ++j)
                    acc[i][j] += a[i] * b[j];
        }
        __syncthreads();
    }

    // epilogue: bias + optional tanh, float4 stores
#pragma unroll
    for (int i = 0; i < TM; ++i) {
        const int m = mbase + trow * TM + i;
        const int n = nbase + tcol * TN;
        float4 v;
        v.x = acc[i][0] + bias[n + 0];
        v.y = acc[i][1] + bias[n + 1];
        v.z = acc[i][2] + bias[n + 2];
        v.w = acc[i][3] + bias[n + 3];
        if (TANH) {
            v.x = tanhf(v.x); v.y = tanhf(v.y); v.z = tanhf(v.z); v.w = tanhf(v.w);
        }
        *(float4*)(C + (size_t)m * N + n) = v;
    }
}

// ---------------------------------------------------------------------------
// Kernel 5: logits = h3[B,384] @ W4[384,3] + b4  (one thread per output elem)
// ---------------------------------------------------------------------------
__global__ void gemm_out_kernel(const float* __restrict__ h3,
                                const float* __restrict__ W4,
                                const float* __restrict__ b4,
                                float* __restrict__ out)
{
    const int idx = blockIdx.x * blockDim.x + threadIdx.x;
    if (idx >= B_ * OUTD) return;
    const int b = idx / OUTD;
    const int o = idx % OUTD;
    float acc = b4[o];
    const float* hr = h3 + (size_t)b * (H_ / 2);
    for (int k = 0; k < H_ / 2; ++k) acc += hr[k] * W4[k * OUTD + o];
    out[idx] = acc;
}

// ---------------------------------------------------------------------------
extern "C" void kernel_launch(void* const* d_in, const int* in_sizes, int n_in,
                              void* d_out, int out_size, void* d_ws, size_t ws_size,
                              hipStream_t stream)
{
    const float* SE       = (const float*)d_in[0];   // [B,S,H]
    const float* pooled   = (const float*)d_in[1];   // [B,H]
    const int*   left_ids = (const int*)  d_in[2];   // [B,LLEFT]
    const int*   t_ids    = (const int*)  d_in[3];   // [B,LT]
    const float* W1 = (const float*)d_in[4];         // [2H,H]
    const float* b1 = (const float*)d_in[5];
    const float* W2 = (const float*)d_in[6];         // [H,H]
    const float* b2 = (const float*)d_in[7];
    const float* W3 = (const float*)d_in[8];         // [H,H/2]
    const float* b3 = (const float*)d_in[9];
    const float* W4 = (const float*)d_in[10];        // [H/2,OUT]
    const float* b4 = (const float*)d_in[11];
    float* out = (float*)d_out;                      // [B,OUT]

    float* ws  = (float*)d_ws;
    float* cat = ws;                          // B * 1536
    float* h1  = cat + B_ * 2 * H_;           // B * 768
    float* h2  = h1 + B_ * H_;                // B * 768
    float* h3  = h2 + B_ * H_;                // B * 384

    // 1) span max-pool + concat
    pool_cat_kernel<<<B_, 256, 0, stream>>>(SE, pooled, left_ids, t_ids, cat);

    // 2) h1 = tanh(cat @ W1 + b1)   M=256 K=1536 N=768
    gemm_bias_act<true><<<dim3(H_ / 64, B_ / 64), 256, 0, stream>>>(cat, W1, b1, h1, B_, H_, 2 * H_);

    // 3) h2 = tanh(h1 @ W2 + b2)    M=256 K=768 N=768
    gemm_bias_act<true><<<dim3(H_ / 64, B_ / 64), 256, 0, stream>>>(h1, W2, b2, h2, B_, H_, H_);

    // 4) h3 = tanh(h2 @ W3 + b3)    M=256 K=768 N=384
    gemm_bias_act<true><<<dim3((H_ / 2) / 64, B_ / 64), 256, 0, stream>>>(h2, W3, b3, h3, B_, H_ / 2, H_);

    // 5) logits = h3 @ W4 + b4      M=256 K=384 N=3
    gemm_out_kernel<<<(B_ * OUTD + 255) / 256, 256, 0, stream>>>(h3, W4, b4, out);
}

// Round 2
// 535.521 us; speedup vs baseline: 1.3146x; 1.3146x over previous
//
#include <hip/hip_runtime.h>
#include <cfloat>

// Problem constants
#define B_    256
#define S_    512
#define H_    768
#define LLEFT 256
#define LT    64
#define OUTD  3

// ---------------------------------------------------------------------------
// Kernel 1: per-batch ragged span max-pool + concat [pooled | span_max]
// One block per batch sample, 256 threads. Ballot-based counts, float4 pool.
// ---------------------------------------------------------------------------
__global__ __launch_bounds__(256)
void pool_cat_kernel(const float* __restrict__ SE,        // [B,S,H]
                     const float* __restrict__ pooled,    // [B,H]
                     const int* __restrict__ left_ids,    // [B,LLEFT]
                     const int* __restrict__ t_ids,       // [B,LT]
                     float* __restrict__ cat)             // [B,2H]
{
    const int b = blockIdx.x;
    const int t = threadIdx.x;

    __shared__ int s_cnt[2];
    if (t < 2) s_cnt[t] = 0;
    __syncthreads();

    // left count: all 4 waves participate (LLEFT == 256)
    {
        unsigned long long m = __ballot(left_ids[b * LLEFT + t] != 0);
        if ((t & 63) == 0) atomicAdd(&s_cnt[0], __popcll(m));
    }
    // target count: wave 0 only (LT == 64)
    if (t < 64) {
        unsigned long long m = __ballot(t_ids[b * LT + t] != 0);
        if (t == 0) s_cnt[1] = __popcll(m);
    }
    __syncthreads();

    const int start = s_cnt[0] - 1;   // left_len
    const int len   = s_cnt[1] - 2;   // target_len  (>=1 by construction)

    const float* se_b = SE + ((size_t)b * S_ + start) * H_;
    // H_/4 = 192 float4 columns
    if (t < H_ / 4) {
        float4 m = make_float4(-FLT_MAX, -FLT_MAX, -FLT_MAX, -FLT_MAX);
        for (int r = 0; r < len; ++r) {
            const float4 v = *(const float4*)(se_b + (size_t)r * H_ + 4 * t);
            m.x = fmaxf(m.x, v.x); m.y = fmaxf(m.y, v.y);
            m.z = fmaxf(m.z, v.z); m.w = fmaxf(m.w, v.w);
        }
        float* cb = cat + (size_t)b * (2 * H_);
        *(float4*)(cb + 4 * t)      = *(const float4*)(pooled + (size_t)b * H_ + 4 * t);
        *(float4*)(cb + H_ + 4 * t) = m;
    }
}

// ---------------------------------------------------------------------------
// Split-K tiled fp32 GEMM partial: P[sk] = A[:, ksk] @ W[ksk, :]
// BM=BN=64, BK=16, 256 threads, 4x4 micro-tile. grid = (N/64, M/64, SK).
// ---------------------------------------------------------------------------
__global__ __launch_bounds__(256)
void gemm_splitk(const float* __restrict__ A,
                 const float* __restrict__ W,
                 float* __restrict__ P,        // [SK, M, N]
                 int M, int N, int K, int Kper)
{
    constexpr int BM = 64, BN = 64, BK = 16, TM = 4, TN = 4;
    __shared__ float As[BK][BM + 4];
    __shared__ float Bs[BK][BN];

    const int tid  = threadIdx.x;
    const int trow = tid / (BN / TN);  // 0..15
    const int tcol = tid % (BN / TN);  // 0..15
    const int mbase = blockIdx.y * BM;
    const int nbase = blockIdx.x * BN;
    const int kbeg  = blockIdx.z * Kper;

    const int a_m = tid >> 2;          // 0..63
    const int a_k = (tid & 3) * 4;     // 0,4,8,12
    const int b_k = tid >> 4;          // 0..15
    const int b_n = (tid & 15) * 4;    // 0..60

    float acc[TM][TN] = {};

    for (int k0 = kbeg; k0 < kbeg + Kper; k0 += BK) {
        const float4 a4 = *(const float4*)(A + (size_t)(mbase + a_m) * K + k0 + a_k);
        As[a_k + 0][a_m] = a4.x;
        As[a_k + 1][a_m] = a4.y;
        As[a_k + 2][a_m] = a4.z;
        As[a_k + 3][a_m] = a4.w;
        *(float4*)&Bs[b_k][b_n] = *(const float4*)(W + (size_t)(k0 + b_k) * N + nbase + b_n);
        __syncthreads();

#pragma unroll
        for (int k = 0; k < BK; ++k) {
            const float4 av = *(const float4*)&As[k][trow * TM];
            const float4 bv = *(const float4*)&Bs[k][tcol * TN];
            const float a[TM] = {av.x, av.y, av.z, av.w};
            const float b[TN] = {bv.x, bv.y, bv.z, bv.w};
#pragma unroll
            for (int i = 0; i < TM; ++i)
#pragma unroll
                for (int j = 0; j < TN; ++j)
                    acc[i][j] += a[i] * b[j];
        }
        __syncthreads();
    }

    float* Pb = P + (size_t)blockIdx.z * M * N;
#pragma unroll
    for (int i = 0; i < TM; ++i) {
        const int m = mbase + trow * TM + i;
        const int n = nbase + tcol * TN;
        float4 v = make_float4(acc[i][0], acc[i][1], acc[i][2], acc[i][3]);
        *(float4*)(Pb + (size_t)m * N + n) = v;
    }
}

// ---------------------------------------------------------------------------
// Reduce over SK partials + bias + tanh. Elementwise over M*N, float4.
// ---------------------------------------------------------------------------
template <bool TANH>
__global__ __launch_bounds__(256)
void reduce_bias_act(const float* __restrict__ P,
                     const float* __restrict__ bias,
                     float* __restrict__ C,
                     int MN, int N, int SK)
{
    const int idx = (blockIdx.x * 256 + threadIdx.x) * 4;
    if (idx >= MN) return;
    float4 v = *(const float4*)(P + idx);
    for (int s = 1; s < SK; ++s) {
        const float4 p = *(const float4*)(P + (size_t)s * MN + idx);
        v.x += p.x; v.y += p.y; v.z += p.z; v.w += p.w;
    }
    const int n = idx % N;
    v.x += bias[n + 0]; v.y += bias[n + 1]; v.z += bias[n + 2]; v.w += bias[n + 3];
    if (TANH) {
        v.x = tanhf(v.x); v.y = tanhf(v.y); v.z = tanhf(v.z); v.w = tanhf(v.w);
    }
    *(float4*)(C + idx) = v;
}

// ---------------------------------------------------------------------------
// Final layer: logits = h3[B,384] @ W4[384,3] + b4. One wave per sample.
// ---------------------------------------------------------------------------
__global__ __launch_bounds__(64)
void out_kernel(const float* __restrict__ h3,
                const float* __restrict__ W4,
                const float* __restrict__ b4,
                float* __restrict__ out)
{
    const int b = blockIdx.x;
    const int lane = threadIdx.x;
    float a0 = 0.f, a1 = 0.f, a2 = 0.f;
    const float* hr = h3 + (size_t)b * (H_ / 2);
#pragma unroll
    for (int k = lane; k < H_ / 2; k += 64) {
        const float h = hr[k];
        a0 += h * W4[k * OUTD + 0];
        a1 += h * W4[k * OUTD + 1];
        a2 += h * W4[k * OUTD + 2];
    }
#pragma unroll
    for (int off = 32; off; off >>= 1) {
        a0 += __shfl_down(a0, off);
        a1 += __shfl_down(a1, off);
        a2 += __shfl_down(a2, off);
    }
    if (lane == 0) {
        out[b * OUTD + 0] = a0 + b4[0];
        out[b * OUTD + 1] = a1 + b4[1];
        out[b * OUTD + 2] = a2 + b4[2];
    }
}

// ---------------------------------------------------------------------------
extern "C" void kernel_launch(void* const* d_in, const int* in_sizes, int n_in,
                              void* d_out, int out_size, void* d_ws, size_t ws_size,
                              hipStream_t stream)
{
    const float* SE       = (const float*)d_in[0];   // [B,S,H]
    const float* pooled   = (const float*)d_in[1];   // [B,H]
    const int*   left_ids = (const int*)  d_in[2];   // [B,LLEFT]
    const int*   t_ids    = (const int*)  d_in[3];   // [B,LT]
    const float* W1 = (const float*)d_in[4];         // [2H,H]
    const float* b1 = (const float*)d_in[5];
    const float* W2 = (const float*)d_in[6];         // [H,H]
    const float* b2 = (const float*)d_in[7];
    const float* W3 = (const float*)d_in[8];         // [H,H/2]
    const float* b3 = (const float*)d_in[9];
    const float* W4 = (const float*)d_in[10];        // [H/2,OUT]
    const float* b4 = (const float*)d_in[11];
    float* out = (float*)d_out;                      // [B,OUT]

    float* ws  = (float*)d_ws;
    float* cat = ws;                          // B*1536 = 393216
    float* h1  = cat + B_ * 2 * H_;           // B*768
    float* h2  = h1 + B_ * H_;                // B*768
    float* h3  = h2 + B_ * H_;                // B*384
    float* Pp  = h3 + B_ * (H_ / 2);          // split-K partials, max 4*256*768 = 786432

    constexpr int SK1 = 4, SK2 = 4, SK3 = 8;

    // 1) span max-pool + concat
    pool_cat_kernel<<<B_, 256, 0, stream>>>(SE, pooled, left_ids, t_ids, cat);

    // 2) h1 = tanh(cat @ W1 + b1)   M=256 K=1536 N=768 ; 48 tiles x SK1 = 192 blocks
    gemm_splitk<<<dim3(H_ / 64, B_ / 64, SK1), 256, 0, stream>>>(cat, W1, Pp, B_, H_, 2 * H_, 2 * H_ / SK1);
    reduce_bias_act<true><<<(B_ * H_ / 4 + 255) / 256, 256, 0, stream>>>(Pp, b1, h1, B_ * H_, H_, SK1);

    // 3) h2 = tanh(h1 @ W2 + b2)    M=256 K=768 N=768 ; 192 blocks
    gemm_splitk<<<dim3(H_ / 64, B_ / 64, SK2), 256, 0, stream>>>(h1, W2, Pp, B_, H_, H_, H_ / SK2);
    reduce_bias_act<true><<<(B_ * H_ / 4 + 255) / 256, 256, 0, stream>>>(Pp, b2, h2, B_ * H_, H_, SK2);

    // 4) h3 = tanh(h2 @ W3 + b3)    M=256 K=768 N=384 ; 24 tiles x SK3 = 192 blocks
    gemm_splitk<<<dim3(H_ / 2 / 64, B_ / 64, SK3), 256, 0, stream>>>(h2, W3, Pp, B_, H_ / 2, H_, H_ / SK3);
    reduce_bias_act<true><<<(B_ * (H_ / 2) / 4 + 255) / 256, 256, 0, stream>>>(Pp, b3, h3, B_ * (H_ / 2), H_ / 2, SK3);

    // 5) logits = h3 @ W4 + b4      one wave per sample
    out_kernel<<<B_, 64, 0, stream>>>(h3, W4, b4, out);
}